// Round 2
// baseline (674.706 us; speedup 1.0000x reference)
//
#include <hip/hip_runtime.h>

// LIF constants folded:
//   i' = s*(1 - DT*TAU_SYN_INV) + x = 0.8*s + x
//   v' = m + DT*TAU_MEM_INV*((0 - m) + i') = 0.9*m + 0.1*i'
//   spike = v' >= 1.0
// Then 2x2 max-pool of the {0,1} spike map (threshold-after-max is equivalent).
//
// Each thread owns a 4-row x 4-col input block (= two vertically adjacent 2x2
// pool tiles) -> 12 independent float4 loads in flight per thread, persistent
// grid-stride over 8 tiles per thread (2048 blocks = 8 blocks/CU exactly
// resident), nontemporal stores so the write stream doesn't evict input L3
// residency. NT store goes through a native ext_vector_type (HIP's float2 is
// a class type the builtin rejects).

constexpr int B = 16, C = 64, H = 256, W = 256;
constexpr int NROWS = B * C * H;              // 262144 input rows
constexpr int ROWF4 = W / 4;                  // 64 float4 per input row
constexpr int NTILES = (NROWS / 4) * ROWF4;   // 4,194,304 tiles (4 rows x 1 f4-col)
constexpr int OWF2 = (W / 2) / 2;             // 64 float2 per output row

typedef float vf2 __attribute__((ext_vector_type(2)));  // native 2-float vector

// v = 0.9*m + 0.1*(0.8*s + x)  (identical fmaf structure to verified kernel)
#define LIF(mm, ss, xx) fmaf(0.9f, (mm), 0.1f * fmaf(0.8f, (ss), (xx)))

__global__ __launch_bounds__(256, 8) void lif_pool_kernel(
    const float4* __restrict__ x,
    const float4* __restrict__ m,
    const float4* __restrict__ s,
    vf2* __restrict__ out)
{
    const int stride = gridDim.x * blockDim.x;  // 524288
    for (int u = blockIdx.x * blockDim.x + threadIdx.x; u < NTILES; u += stride) {
        const int rg  = u >> 6;          // row-group: input rows 4*rg .. 4*rg+3
        const int ocp = u & 63;          // float4 column within the row
        const int i0  = rg * (4 * ROWF4) + ocp;

        // 12 independent, fully coalesced loads (each wave-load = one 1KB row)
        float4 x0 = x[i0], x1 = x[i0 + ROWF4], x2 = x[i0 + 2 * ROWF4], x3 = x[i0 + 3 * ROWF4];
        float4 m0 = m[i0], m1 = m[i0 + ROWF4], m2 = m[i0 + 2 * ROWF4], m3 = m[i0 + 3 * ROWF4];
        float4 s0 = s[i0], s1 = s[i0 + ROWF4], s2 = s[i0 + 2 * ROWF4], s3 = s[i0 + 3 * ROWF4];

        // membrane voltages
        float v00 = LIF(m0.x, s0.x, x0.x), v01 = LIF(m0.y, s0.y, x0.y);
        float v02 = LIF(m0.z, s0.z, x0.z), v03 = LIF(m0.w, s0.w, x0.w);
        float v10 = LIF(m1.x, s1.x, x1.x), v11 = LIF(m1.y, s1.y, x1.y);
        float v12 = LIF(m1.z, s1.z, x1.z), v13 = LIF(m1.w, s1.w, x1.w);
        float v20 = LIF(m2.x, s2.x, x2.x), v21 = LIF(m2.y, s2.y, x2.y);
        float v22 = LIF(m2.z, s2.z, x2.z), v23 = LIF(m2.w, s2.w, x2.w);
        float v30 = LIF(m3.x, s3.x, x3.x), v31 = LIF(m3.y, s3.y, x3.y);
        float v32 = LIF(m3.z, s3.z, x3.z), v33 = LIF(m3.w, s3.w, x3.w);

        // 2x2 max-pool, then threshold
        float a0 = fmaxf(fmaxf(v00, v01), fmaxf(v10, v11));  // out row 2*rg,   col 2*ocp
        float a1 = fmaxf(fmaxf(v02, v03), fmaxf(v12, v13));  // out row 2*rg,   col 2*ocp+1
        float b0 = fmaxf(fmaxf(v20, v21), fmaxf(v30, v31));  // out row 2*rg+1, col 2*ocp
        float b1 = fmaxf(fmaxf(v22, v23), fmaxf(v32, v33));  // out row 2*rg+1, col 2*ocp+1

        vf2 oa, ob;
        oa.x = (a0 >= 1.0f) ? 1.0f : 0.0f;
        oa.y = (a1 >= 1.0f) ? 1.0f : 0.0f;
        ob.x = (b0 >= 1.0f) ? 1.0f : 0.0f;
        ob.y = (b1 >= 1.0f) ? 1.0f : 0.0f;

        // output rows 2*rg and 2*rg+1; nontemporal: output is never re-read
        __builtin_nontemporal_store(oa, &out[(2 * rg)     * OWF2 + ocp]);
        __builtin_nontemporal_store(ob, &out[(2 * rg + 1) * OWF2 + ocp]);
    }
}

extern "C" void kernel_launch(void* const* d_in, const int* in_sizes, int n_in,
                              void* d_out, int out_size, void* d_ws, size_t ws_size,
                              hipStream_t stream) {
    const float4* x = (const float4*)d_in[0];  // input_signal
    const float4* m = (const float4*)d_in[1];  // membrane
    const float4* s = (const float4*)d_in[2];  // synaptic
    vf2* out = (vf2*)d_out;

    constexpr int BLOCK = 256;
    constexpr int GRID = 2048;  // 8 blocks/CU on 256 CUs, grid-stride covers 8 tiles/thread
    lif_pool_kernel<<<GRID, BLOCK, 0, stream>>>(x, m, s, out);
}

// Round 3
// 646.423 us; speedup vs baseline: 1.0438x; 1.0438x over previous
//
#include <hip/hip_runtime.h>

// LIF constants folded:
//   i' = s*(1 - DT*TAU_SYN_INV) + x = 0.8*s + x
//   v' = m + DT*TAU_MEM_INV*((0 - m) + i') = 0.9*m + 0.1*i'
//   spike = v' >= 1.0
// Then 2x2 max-pool of the {0,1} spike map.
//
// Round-3: EXACT round-0 structure (known best, 216 us/dispatch) with ONE
// change: nontemporal loads on the three input streams. Inputs are streamed
// once with zero intra-dispatch reuse; nt skips L2-allocate churn. This is
// also the discriminating experiment for whether FETCH_SIZE==half-of-reads
// is a counter artifact (then this is neutral/mild win) or real cache hits
// (then this regresses and round-0 is the roofline kernel).

constexpr int B = 16, C = 64, H = 256, W = 256;
constexpr int OW = W / 2;                        // 128
constexpr int NROWS = B * C * H;                 // input rows (flattened over b,c,h)
constexpr int NTHREADS = (NROWS / 2) * (OW / 2); // 1 thread = 2 output px = 2x4 input block

typedef float vf4 __attribute__((ext_vector_type(4)));  // native 4-float vector
typedef float vf2 __attribute__((ext_vector_type(2)));  // native 2-float vector

__global__ __launch_bounds__(256) void lif_pool_kernel(
    const vf4* __restrict__ x,
    const vf4* __restrict__ m,
    const vf4* __restrict__ s,
    vf2* __restrict__ out)
{
    int t = blockIdx.x * blockDim.x + threadIdx.x;
    if (t >= NTHREADS) return;

    int orow = t >> 6;   // output row index (64 float4-wide thread slots per row)
    int ocp  = t & 63;   // which float4 within the row

    // input float4 index: rows 2*orow and 2*orow+1, col group ocp (64 float4 per row)
    int i0 = (2 * orow) * (W / 4) + ocp;
    int i1 = i0 + (W / 4);

    vf4 x0 = __builtin_nontemporal_load(&x[i0]);
    vf4 x1 = __builtin_nontemporal_load(&x[i1]);
    vf4 m0 = __builtin_nontemporal_load(&m[i0]);
    vf4 m1 = __builtin_nontemporal_load(&m[i1]);
    vf4 s0 = __builtin_nontemporal_load(&s[i0]);
    vf4 s1 = __builtin_nontemporal_load(&s[i1]);

    // v = 0.9*m + 0.1*(0.8*s + x)   (identical fmaf structure to verified kernel)
    float v00 = fmaf(0.9f, m0.x, 0.1f * fmaf(0.8f, s0.x, x0.x));
    float v01 = fmaf(0.9f, m0.y, 0.1f * fmaf(0.8f, s0.y, x0.y));
    float v02 = fmaf(0.9f, m0.z, 0.1f * fmaf(0.8f, s0.z, x0.z));
    float v03 = fmaf(0.9f, m0.w, 0.1f * fmaf(0.8f, s0.w, x0.w));
    float v10 = fmaf(0.9f, m1.x, 0.1f * fmaf(0.8f, s1.x, x1.x));
    float v11 = fmaf(0.9f, m1.y, 0.1f * fmaf(0.8f, s1.y, x1.y));
    float v12 = fmaf(0.9f, m1.z, 0.1f * fmaf(0.8f, s1.z, x1.z));
    float v13 = fmaf(0.9f, m1.w, 0.1f * fmaf(0.8f, s1.w, x1.w));

    // pooled spike = (max of 4 v's in the 2x2 window) >= 1.0 ? 1 : 0
    float w0 = fmaxf(fmaxf(v00, v01), fmaxf(v10, v11));
    float w1 = fmaxf(fmaxf(v02, v03), fmaxf(v12, v13));

    vf2 o;
    o.x = (w0 >= 1.0f) ? 1.0f : 0.0f;
    o.y = (w1 >= 1.0f) ? 1.0f : 0.0f;

    out[orow * (OW / 2) + ocp] = o;  // out row has 128 floats = 64 float2
}

extern "C" void kernel_launch(void* const* d_in, const int* in_sizes, int n_in,
                              void* d_out, int out_size, void* d_ws, size_t ws_size,
                              hipStream_t stream) {
    const vf4* x = (const vf4*)d_in[0];  // input_signal
    const vf4* m = (const vf4*)d_in[1];  // membrane
    const vf4* s = (const vf4*)d_in[2];  // synaptic
    vf2* out = (vf2*)d_out;

    constexpr int BLOCK = 256;
    constexpr int GRID = (NTHREADS + BLOCK - 1) / BLOCK;  // 32768
    lif_pool_kernel<<<GRID, BLOCK, 0, stream>>>(x, m, s, out);
}

// Round 4
// 634.435 us; speedup vs baseline: 1.0635x; 1.0189x over previous
//
#include <hip/hip_runtime.h>

// LIF constants folded:
//   i' = s*(1 - DT*TAU_SYN_INV) + x = 0.8*s + x
//   v' = m + DT*TAU_MEM_INV*((0 - m) + i') = 0.9*m + 0.1*i'
//   spike = v' >= 1.0
// Then 2x2 max-pool of the {0,1} spike map.
//
// Round-4: round-3 winner (NT loads, 161.5 us/dispatch) + ONE change:
// nontemporal STORES on the output stream (the only remaining isolated,
// byte-neutral knob). Output is write-once, never re-read -> stream it out
// without L2/L3 allocation so the 64 MiB write stream doesn't steal
// allocate bandwidth from the 768 MiB read stream.

constexpr int B = 16, C = 64, H = 256, W = 256;
constexpr int OW = W / 2;                        // 128
constexpr int NROWS = B * C * H;                 // input rows (flattened over b,c,h)
constexpr int NTHREADS = (NROWS / 2) * (OW / 2); // 1 thread = 2 output px = 2x4 input block

typedef float vf4 __attribute__((ext_vector_type(4)));  // native 4-float vector
typedef float vf2 __attribute__((ext_vector_type(2)));  // native 2-float vector

__global__ __launch_bounds__(256) void lif_pool_kernel(
    const vf4* __restrict__ x,
    const vf4* __restrict__ m,
    const vf4* __restrict__ s,
    vf2* __restrict__ out)
{
    int t = blockIdx.x * blockDim.x + threadIdx.x;
    if (t >= NTHREADS) return;

    int orow = t >> 6;   // output row index (64 float4-wide thread slots per row)
    int ocp  = t & 63;   // which float4 within the row

    // input float4 index: rows 2*orow and 2*orow+1, col group ocp (64 float4 per row)
    int i0 = (2 * orow) * (W / 4) + ocp;
    int i1 = i0 + (W / 4);

    vf4 x0 = __builtin_nontemporal_load(&x[i0]);
    vf4 x1 = __builtin_nontemporal_load(&x[i1]);
    vf4 m0 = __builtin_nontemporal_load(&m[i0]);
    vf4 m1 = __builtin_nontemporal_load(&m[i1]);
    vf4 s0 = __builtin_nontemporal_load(&s[i0]);
    vf4 s1 = __builtin_nontemporal_load(&s[i1]);

    // v = 0.9*m + 0.1*(0.8*s + x)   (identical fmaf structure to verified kernel)
    float v00 = fmaf(0.9f, m0.x, 0.1f * fmaf(0.8f, s0.x, x0.x));
    float v01 = fmaf(0.9f, m0.y, 0.1f * fmaf(0.8f, s0.y, x0.y));
    float v02 = fmaf(0.9f, m0.z, 0.1f * fmaf(0.8f, s0.z, x0.z));
    float v03 = fmaf(0.9f, m0.w, 0.1f * fmaf(0.8f, s0.w, x0.w));
    float v10 = fmaf(0.9f, m1.x, 0.1f * fmaf(0.8f, s1.x, x1.x));
    float v11 = fmaf(0.9f, m1.y, 0.1f * fmaf(0.8f, s1.y, x1.y));
    float v12 = fmaf(0.9f, m1.z, 0.1f * fmaf(0.8f, s1.z, x1.z));
    float v13 = fmaf(0.9f, m1.w, 0.1f * fmaf(0.8f, s1.w, x1.w));

    // pooled spike = (max of 4 v's in the 2x2 window) >= 1.0 ? 1 : 0
    float w0 = fmaxf(fmaxf(v00, v01), fmaxf(v10, v11));
    float w1 = fmaxf(fmaxf(v02, v03), fmaxf(v12, v13));

    vf2 o;
    o.x = (w0 >= 1.0f) ? 1.0f : 0.0f;
    o.y = (w1 >= 1.0f) ? 1.0f : 0.0f;

    __builtin_nontemporal_store(o, &out[orow * (OW / 2) + ocp]);
}

extern "C" void kernel_launch(void* const* d_in, const int* in_sizes, int n_in,
                              void* d_out, int out_size, void* d_ws, size_t ws_size,
                              hipStream_t stream) {
    const vf4* x = (const vf4*)d_in[0];  // input_signal
    const vf4* m = (const vf4*)d_in[1];  // membrane
    const vf4* s = (const vf4*)d_in[2];  // synaptic
    vf2* out = (vf2*)d_out;

    constexpr int BLOCK = 256;
    constexpr int GRID = (NTHREADS + BLOCK - 1) / BLOCK;  // 32768
    lif_pool_kernel<<<GRID, BLOCK, 0, stream>>>(x, m, s, out);
}